// Round 2
// baseline (560.417 us; speedup 1.0000x reference)
//
#include <hip/hip_runtime.h>
#include <math.h>

#define NTOK 2048
#define DM   1024
#define NH   16
#define DH   64
#define GM   2048
#define GN   1024
#define GK   1024
#define SCALE 0.125f

typedef __attribute__((ext_vector_type(8))) short short8;
typedef __attribute__((ext_vector_type(4))) float floatx4;
typedef unsigned short ushort_t;

__device__ __forceinline__ unsigned short f2bf(float f) {
    unsigned u = __builtin_bit_cast(unsigned, f);
    u += 0x7fffu + ((u >> 16) & 1u);   // RNE
    return (unsigned short)(u >> 16);
}

// ---------------------------------------------------------------------------
// convert fp32 -> bf16 for [x | Wq | Wk | Wv | Wo] into contiguous ws region
// ---------------------------------------------------------------------------
__global__ __launch_bounds__(256) void convert5(
    const float* __restrict__ x,  const float* __restrict__ wq,
    const float* __restrict__ wk, const float* __restrict__ wv,
    const float* __restrict__ wo, ushort_t* __restrict__ dst)
{
    const size_t i4 = (size_t)blockIdx.x * 256 + threadIdx.x;  // float4 index
    const float* src; size_t off;
    if      (i4 <  524288) { src = x;  off = 0;       }
    else if (i4 <  786432) { src = wq; off = 524288;  }
    else if (i4 < 1048576) { src = wk; off = 786432;  }
    else if (i4 < 1310720) { src = wv; off = 1048576; }
    else                   { src = wo; off = 1310720; }
    float4 v = ((const float4*)src)[i4 - off];
    ushort4 o;
    o.x = f2bf(v.x); o.y = f2bf(v.y); o.z = f2bf(v.z); o.w = f2bf(v.w);
    ((ushort4*)dst)[i4] = o;
}

// ---------------------------------------------------------------------------
// bf16 MFMA GEMM: C = A @ B^T + bias. Templated tile (BM x BN), BK=32,
// 256 thr = 4 waves in 2x2. modes: 0 bf16 [M][N], 1 bf16 transposed [N][M],
// 2 fp32 [M][N]. blockIdx.z picks B/bias/C/mode (QKV in one launch).
// ---------------------------------------------------------------------------
template<int BM, int BN>
__global__ __launch_bounds__(256) void gemm_bt(
    const ushort_t* __restrict__ A,
    const ushort_t* __restrict__ B0, const ushort_t* __restrict__ B1,
    const ushort_t* __restrict__ B2,
    const float* __restrict__ bi0, const float* __restrict__ bi1,
    const float* __restrict__ bi2,
    void* C0, void* C1, void* C2, int mode0, int mode1, int mode2)
{
    constexpr int AC = BM * 4 / 256;   // A 16B-chunks per thread
    constexpr int BC = BN * 4 / 256;
    constexpr int FI = BM / 32;        // frags per wave (rows)
    constexpr int FJ = BN / 32;        // frags per wave (cols)
    constexpr int WM = BM / 2;
    constexpr int WN = BN / 2;

    const int z = blockIdx.z;
    const ushort_t* B   = (z == 0) ? B0  : (z == 1) ? B1  : B2;
    const float*    bia = (z == 0) ? bi0 : (z == 1) ? bi1 : bi2;
    void*           C   = (z == 0) ? C0  : (z == 1) ? C1  : C2;
    const int mode      = (z == 0) ? mode0 : (z == 1) ? mode1 : mode2;

    __shared__ __align__(16) ushort_t As[BM][32];
    __shared__ __align__(16) ushort_t Bs[BN][32];

    const int t    = threadIdx.x;
    const int w    = t >> 6;
    const int L    = t & 63;
    const int r16  = L & 15;
    const int quad = L >> 4;
    const int wm   = w & 1;
    const int wn   = w >> 1;

    const int m0 = blockIdx.y * BM;
    const int n0 = blockIdx.x * BN;

    const int srow = t >> 2;        // staging row (+ c*64)
    const int skc  = (t & 3) * 8;   // k element offset

    const ushort_t* ap = A + (size_t)(m0 + srow) * GK + skc;
    const ushort_t* bp = B + (size_t)(n0 + srow) * GK + skc;

    floatx4 acc[FI][FJ];
#pragma unroll
    for (int i = 0; i < FI; ++i)
#pragma unroll
        for (int j = 0; j < FJ; ++j) acc[i][j] = (floatx4){0.f, 0.f, 0.f, 0.f};

    short8 areg[AC], breg[BC];
#pragma unroll
    for (int c = 0; c < AC; ++c) areg[c] = *(const short8*)(ap + (size_t)c * 64 * GK);
#pragma unroll
    for (int c = 0; c < BC; ++c) breg[c] = *(const short8*)(bp + (size_t)c * 64 * GK);

    for (int ks = 0; ks < GK / 32; ++ks) {
        __syncthreads();
#pragma unroll
        for (int c = 0; c < AC; ++c) *(short8*)&As[c * 64 + srow][skc] = areg[c];
#pragma unroll
        for (int c = 0; c < BC; ++c) *(short8*)&Bs[c * 64 + srow][skc] = breg[c];
        __syncthreads();
        if (ks < GK / 32 - 1) {
            ap += 32; bp += 32;
#pragma unroll
            for (int c = 0; c < AC; ++c) areg[c] = *(const short8*)(ap + (size_t)c * 64 * GK);
#pragma unroll
            for (int c = 0; c < BC; ++c) breg[c] = *(const short8*)(bp + (size_t)c * 64 * GK);
        }
        short8 af[FI], bf[FJ];
#pragma unroll
        for (int fi = 0; fi < FI; ++fi)
            af[fi] = *(const short8*)&As[wm * WM + fi * 16 + r16][quad * 8];
#pragma unroll
        for (int fj = 0; fj < FJ; ++fj)
            bf[fj] = *(const short8*)&Bs[wn * WN + fj * 16 + r16][quad * 8];
#pragma unroll
        for (int fi = 0; fi < FI; ++fi)
#pragma unroll
            for (int fj = 0; fj < FJ; ++fj)
                acc[fi][fj] = __builtin_amdgcn_mfma_f32_16x16x32_bf16(
                    af[fi], bf[fj], acc[fi][fj], 0, 0, 0);
    }

#pragma unroll
    for (int fj = 0; fj < FJ; ++fj) {
        const int col = n0 + wn * WN + fj * 16 + r16;
        const float bv = bia[col];
#pragma unroll
        for (int fi = 0; fi < FI; ++fi) {
            const int row0 = m0 + wm * WM + fi * 16 + 4 * quad;
            floatx4 c = acc[fi][fj];
            if (mode == 2) {
                float* Cf = (float*)C;
#pragma unroll
                for (int i = 0; i < 4; ++i)
                    Cf[(size_t)(row0 + i) * GN + col] = c[i] + bv;
            } else if (mode == 0) {
                ushort_t* Cb = (ushort_t*)C;
#pragma unroll
                for (int i = 0; i < 4; ++i)
                    Cb[(size_t)(row0 + i) * GN + col] = f2bf(c[i] + bv);
            } else {  // transposed: vT[col][token]
                ushort_t* Cb = (ushort_t*)C;
                ushort4 pk;
                pk.x = f2bf(c[0] + bv); pk.y = f2bf(c[1] + bv);
                pk.z = f2bf(c[2] + bv); pk.w = f2bf(c[3] + bv);
                *(ushort4*)(Cb + (size_t)col * GM + row0) = pk;
            }
        }
    }
}

// ---------------------------------------------------------------------------
// MFMA flash attention, fixed-max softmax (m=0), split-j over NCH chunks.
// NEW: block = 1024 threads = 16 waves = ALL 16 heads for one 16-row i-tile.
// The bias tile [16 i][32 j][16 h] is CONTIGUOUS in memory (h innermost), so
// staging is fully dense float4 loads (100% line utilization) instead of the
// old 16B-per-64B gather (64 scattered lines per wave-instr) that saturated
// the per-CU vector-memory path. Wave w = head w; per-wave compute structure
// (direct global->VGPR K/V frags, LDS P transpose, fp32 partials) unchanged.
// ---------------------------------------------------------------------------
#define NT   (NTOK / 32)
#define NCH  4
#define NTCH (NT / NCH)          // 16 j-tiles per chunk
#define JCH  (NTOK / NCH)        // 512 columns per chunk

__global__ __launch_bounds__(1024) void attn3(
    const ushort_t* __restrict__ q, const ushort_t* __restrict__ k,
    const ushort_t* __restrict__ vT, const float* __restrict__ bias,
    float* __restrict__ opart, float* __restrict__ lpart)
{
    __shared__ float    Bb[2][16][16][33];  // [buf][head][i][j pad33]  67.6 KB
    __shared__ ushort_t Ps[16][16][40];     // [wave][row][col pad40]   20.5 KB

    const int it   = blockIdx.x;
    const int ch   = blockIdx.y;
    const int jb   = ch * JCH;
    const int i0   = it * 16;
    const int t    = threadIdx.x;
    const int w    = t >> 6;        // wave index = head
    const int L    = t & 63;
    const int r16  = L & 15;
    const int quad = L >> 4;
    const int h    = w;

    // bias staging coords: thread stages 8 heads of one (i,j) cell
    const int si = t >> 6;          // i row (= wave index)
    const int sj = (L >> 1);        // j col 0..31
    const int sh = (L & 1) * 8;     // h start 0 or 8

#define kAddr(J0, JH, KC) (k  + (size_t)((J0) + (JH)*16 + r16) * DM + h*DH + (KC)*32 + quad*8)
#define vAddr(J0, DB)     (vT + (size_t)(h*DH + (DB)*16 + r16) * NTOK + (J0) + quad*8)
#define bAddr(J0)         (bias + ((size_t)(i0 + si) * NTOK + (J0) + sj) * NH + sh)

    // resident Q A-frags
    short8 qf[2];
#pragma unroll
    for (int kc = 0; kc < 2; ++kc)
        qf[kc] = *(const short8*)(q + (size_t)(i0 + r16) * DM + h * DH + kc * 32 + quad * 8);

    short8 kf[2][4];   // [buf][jh*2+kc]
    short8 vf[2][4];   // [buf][db]
    float4 bst[2];

    // prologue: first tile of this chunk
    kf[0][0] = *(const short8*)kAddr(jb, 0, 0);
    kf[0][1] = *(const short8*)kAddr(jb, 0, 1);
    kf[0][2] = *(const short8*)kAddr(jb, 1, 0);
    kf[0][3] = *(const short8*)kAddr(jb, 1, 1);
    vf[0][0] = *(const short8*)vAddr(jb, 0);
    vf[0][1] = *(const short8*)vAddr(jb, 1);
    vf[0][2] = *(const short8*)vAddr(jb, 2);
    vf[0][3] = *(const short8*)vAddr(jb, 3);
    bst[0] = *(const float4*)bAddr(jb);
    bst[1] = *(const float4*)(bAddr(jb) + 4);
    Bb[0][sh + 0][si][sj] = bst[0].x;
    Bb[0][sh + 1][si][sj] = bst[0].y;
    Bb[0][sh + 2][si][sj] = bst[0].z;
    Bb[0][sh + 3][si][sj] = bst[0].w;
    Bb[0][sh + 4][si][sj] = bst[1].x;
    Bb[0][sh + 5][si][sj] = bst[1].y;
    Bb[0][sh + 6][si][sj] = bst[1].z;
    Bb[0][sh + 7][si][sj] = bst[1].w;
    __syncthreads();

    floatx4 o[4];
#pragma unroll
    for (int d = 0; d < 4; ++d) o[d] = (floatx4){0.f, 0.f, 0.f, 0.f};
    float lrow[4] = {0.f, 0.f, 0.f, 0.f};

#define TILE(JT, CUR, NXT)                                                      \
  {                                                                             \
    const bool pre = (JT) < NTCH - 1;                                           \
    const int j0n = jb + ((JT) + 1) * 32;                                       \
    if (pre) {                                                                  \
      kf[NXT][0] = *(const short8*)kAddr(j0n, 0, 0);                            \
      kf[NXT][1] = *(const short8*)kAddr(j0n, 0, 1);                            \
      kf[NXT][2] = *(const short8*)kAddr(j0n, 1, 0);                            \
      kf[NXT][3] = *(const short8*)kAddr(j0n, 1, 1);                            \
      vf[NXT][0] = *(const short8*)vAddr(j0n, 0);                               \
      vf[NXT][1] = *(const short8*)vAddr(j0n, 1);                               \
      vf[NXT][2] = *(const short8*)vAddr(j0n, 2);                               \
      vf[NXT][3] = *(const short8*)vAddr(j0n, 3);                               \
      bst[0] = *(const float4*)bAddr(j0n);                                      \
      bst[1] = *(const float4*)(bAddr(j0n) + 4);                                \
    }                                                                           \
    floatx4 s0 = (floatx4){0.f, 0.f, 0.f, 0.f};                                 \
    floatx4 s1 = (floatx4){0.f, 0.f, 0.f, 0.f};                                 \
    s0 = __builtin_amdgcn_mfma_f32_16x16x32_bf16(qf[0], kf[CUR][0], s0, 0,0,0); \
    s0 = __builtin_amdgcn_mfma_f32_16x16x32_bf16(qf[1], kf[CUR][1], s0, 0,0,0); \
    s1 = __builtin_amdgcn_mfma_f32_16x16x32_bf16(qf[0], kf[CUR][2], s1, 0,0,0); \
    s1 = __builtin_amdgcn_mfma_f32_16x16x32_bf16(qf[1], kf[CUR][3], s1, 0,0,0); \
    _Pragma("unroll")                                                           \
    for (int ii = 0; ii < 4; ++ii) {                                            \
      const float bv0 = Bb[CUR][w][4 * quad + ii][r16];                         \
      const float bv1 = Bb[CUR][w][4 * quad + ii][16 + r16];                    \
      const float p0 = __expf(fmaf(s0[ii], SCALE, bv0));                        \
      const float p1 = __expf(fmaf(s1[ii], SCALE, bv1));                        \
      lrow[ii] += p0 + p1;                                                      \
      Ps[w][4 * quad + ii][r16]      = f2bf(p0);                                \
      Ps[w][4 * quad + ii][16 + r16] = f2bf(p1);                                \
    }                                                                           \
    short8 pf = *(const short8*)&Ps[w][r16][quad * 8];                          \
    o[0] = __builtin_amdgcn_mfma_f32_16x16x32_bf16(pf, vf[CUR][0], o[0], 0,0,0);\
    o[1] = __builtin_amdgcn_mfma_f32_16x16x32_bf16(pf, vf[CUR][1], o[1], 0,0,0);\
    o[2] = __builtin_amdgcn_mfma_f32_16x16x32_bf16(pf, vf[CUR][2], o[2], 0,0,0);\
    o[3] = __builtin_amdgcn_mfma_f32_16x16x32_bf16(pf, vf[CUR][3], o[3], 0,0,0);\
    if (pre) {                                                                  \
      Bb[NXT][sh + 0][si][sj] = bst[0].x;                                       \
      Bb[NXT][sh + 1][si][sj] = bst[0].y;                                       \
      Bb[NXT][sh + 2][si][sj] = bst[0].z;                                       \
      Bb[NXT][sh + 3][si][sj] = bst[0].w;                                       \
      Bb[NXT][sh + 4][si][sj] = bst[1].x;                                       \
      Bb[NXT][sh + 5][si][sj] = bst[1].y;                                       \
      Bb[NXT][sh + 6][si][sj] = bst[1].z;                                       \
      Bb[NXT][sh + 7][si][sj] = bst[1].w;                                       \
    }                                                                           \
    __syncthreads();                                                            \
  }

    for (int jt = 0; jt < NTCH; jt += 2) {
        TILE(jt, 0, 1)
        TILE(jt + 1, 1, 0)
    }

    // partial row-sum: reduce l across the 16 column-lanes of each row
    float lred[4];
#pragma unroll
    for (int ii = 0; ii < 4; ++ii) {
        float s = lrow[ii];
#pragma unroll
        for (int d = 1; d < 16; d <<= 1) s += __shfl_xor(s, d);
        lred[ii] = s;
    }
    if (r16 == 0) {
#pragma unroll
        for (int ii = 0; ii < 4; ++ii)
            lpart[(size_t)ch * NH * NTOK + (size_t)h * NTOK + i0 + 4 * quad + ii] = lred[ii];
    }

    float* op = opart + (size_t)ch * NTOK * DM;
#pragma unroll
    for (int db = 0; db < 4; ++db)
#pragma unroll
        for (int ii = 0; ii < 4; ++ii)
            op[(size_t)(i0 + 4 * quad + ii) * DM + h * DH + db * 16 + r16] = o[db][ii];
#undef TILE
#undef kAddr
#undef vAddr
#undef bAddr
}

// ---------------------------------------------------------------------------
// merge split-j partials: o = (sum_c opart[c]) / (sum_c lpart[c]); bf16 out.
// ---------------------------------------------------------------------------
__global__ __launch_bounds__(256) void attn_fin(
    const float* __restrict__ opart, const float* __restrict__ lpart,
    ushort_t* __restrict__ ao)
{
    const int idx = blockIdx.x * 256 + threadIdx.x;   // float4 index
    const int n   = idx >> 8;                         // 256 float4 per row
    const int d4  = idx & 255;
    const int h   = d4 >> 4;
    const size_t base = (size_t)n * DM + (size_t)d4 * 4;
    float4 s = {0.f, 0.f, 0.f, 0.f};
    float  l = 0.f;
#pragma unroll
    for (int c = 0; c < NCH; ++c) {
        float4 p = *(const float4*)(opart + (size_t)c * NTOK * DM + base);
        s.x += p.x; s.y += p.y; s.z += p.z; s.w += p.w;
        l += lpart[(size_t)c * NH * NTOK + (size_t)h * NTOK + n];
    }
    const float inv = 1.f / l;
    ushort4 o;
    o.x = f2bf(s.x * inv); o.y = f2bf(s.y * inv);
    o.z = f2bf(s.z * inv); o.w = f2bf(s.w * inv);
    ((ushort4*)ao)[idx] = o;
}

// ---------------------------------------------------------------------------
// launch
// ---------------------------------------------------------------------------
extern "C" void kernel_launch(void* const* d_in, const int* in_sizes, int n_in,
                              void* d_out, int out_size, void* d_ws, size_t ws_size,
                              hipStream_t stream)
{
    const float* x  = (const float*)d_in[0];
    const float* eb = (const float*)d_in[1];
    const float* Wq = (const float*)d_in[2];
    const float* bq = (const float*)d_in[3];
    const float* Wk = (const float*)d_in[4];
    const float* bk = (const float*)d_in[5];
    const float* Wv = (const float*)d_in[6];
    const float* bv = (const float*)d_in[7];
    const float* Wo = (const float*)d_in[8];
    const float* bo = (const float*)d_in[9];
    float* out = (float*)d_out;
    (void)in_sizes; (void)n_in; (void)out_size; (void)ws_size;

    const size_t E1 = (size_t)1024 * 1024;
    ushort_t* wsb = (ushort_t*)d_ws;
    ushort_t* xb  = wsb;            // 2M
    ushort_t* Wqb = wsb + 2 * E1;   // 1M each
    ushort_t* Wkb = wsb + 3 * E1;
    ushort_t* Wvb = wsb + 4 * E1;
    ushort_t* Wob = wsb + 5 * E1;
    ushort_t* qb  = wsb + 6 * E1;   // 2M each
    ushort_t* kb  = wsb + 8 * E1;
    ushort_t* vTb = wsb + 10 * E1;
    ushort_t* aob = wsb + 12 * E1;
    // split-j partials after aob: NCH x [N][DM] fp32 + NCH x [NH][N] fp32
    float* opart = (float*)(wsb + 14 * E1);
    float* lpart = opart + (size_t)NCH * NTOK * DM;

    convert5<<<6144, 256, 0, stream>>>(x, Wq, Wk, Wv, Wo, wsb);

    // QKV projections: 128x64 tiles -> grid 16x16x3 = 768 blocks (3/CU)
    {
        dim3 grid(GN / 64, GM / 128, 3);
        gemm_bt<128, 64><<<grid, 256, 0, stream>>>(
            xb, Wqb, Wkb, Wvb, bq, bk, bv,
            qb, kb, vTb, 0, 0, 1);
    }
    // fused attention: 16-wave blocks (all heads of one i-tile), split-j
    {
        dim3 grid(NTOK / 16, NCH, 1);
        attn3<<<grid, 1024, 0, stream>>>(qb, kb, vTb, eb, opart, lpart);
    }
    attn_fin<<<NTOK * DM / 4 / 256, 256, 0, stream>>>(opart, lpart, aob);

    // output projection: 64x64 tiles -> grid 16x32 = 512 blocks (2/CU)
    {
        dim3 grid(GN / 64, GM / 64, 1);
        gemm_bt<64, 64><<<grid, 256, 0, stream>>>(
            aob, Wob, Wob, Wob, bo, bo, bo,
            out, out, out, 2, 2, 2);
    }
}

// Round 3
// 496.256 us; speedup vs baseline: 1.1293x; 1.1293x over previous
//
#include <hip/hip_runtime.h>
#include <math.h>

#define NTOK 2048
#define DM   1024
#define NH   16
#define DH   64
#define GM   2048
#define GN   1024
#define GK   1024
#define SCALE 0.125f

typedef __attribute__((ext_vector_type(8))) short short8;
typedef __attribute__((ext_vector_type(4))) float floatx4;
typedef unsigned short ushort_t;

__device__ __forceinline__ unsigned short f2bf(float f) {
    unsigned u = __builtin_bit_cast(unsigned, f);
    u += 0x7fffu + ((u >> 16) & 1u);   // RNE
    return (unsigned short)(u >> 16);
}

// ---------------------------------------------------------------------------
// convert fp32 -> bf16 for [x | Wq | Wk | Wv | Wo] into contiguous ws region
// ---------------------------------------------------------------------------
__global__ __launch_bounds__(256) void convert5(
    const float* __restrict__ x,  const float* __restrict__ wq,
    const float* __restrict__ wk, const float* __restrict__ wv,
    const float* __restrict__ wo, ushort_t* __restrict__ dst)
{
    const size_t i4 = (size_t)blockIdx.x * 256 + threadIdx.x;  // float4 index
    const float* src; size_t off;
    if      (i4 <  524288) { src = x;  off = 0;       }
    else if (i4 <  786432) { src = wq; off = 524288;  }
    else if (i4 < 1048576) { src = wk; off = 786432;  }
    else if (i4 < 1310720) { src = wv; off = 1048576; }
    else                   { src = wo; off = 1310720; }
    float4 v = ((const float4*)src)[i4 - off];
    ushort4 o;
    o.x = f2bf(v.x); o.y = f2bf(v.y); o.z = f2bf(v.z); o.w = f2bf(v.w);
    ((ushort4*)dst)[i4] = o;
}

// ---------------------------------------------------------------------------
// bf16 MFMA GEMM: C = A @ B^T + bias. Templated tile (BM x BN), BK=32,
// 256 thr = 4 waves in 2x2. modes: 0 bf16 [M][N], 1 bf16 transposed [N][M],
// 2 fp32 [M][N]. blockIdx.z picks B/bias/C/mode (QKV in one launch).
// ---------------------------------------------------------------------------
template<int BM, int BN>
__global__ __launch_bounds__(256) void gemm_bt(
    const ushort_t* __restrict__ A,
    const ushort_t* __restrict__ B0, const ushort_t* __restrict__ B1,
    const ushort_t* __restrict__ B2,
    const float* __restrict__ bi0, const float* __restrict__ bi1,
    const float* __restrict__ bi2,
    void* C0, void* C1, void* C2, int mode0, int mode1, int mode2)
{
    constexpr int AC = BM * 4 / 256;   // A 16B-chunks per thread
    constexpr int BC = BN * 4 / 256;
    constexpr int FI = BM / 32;        // frags per wave (rows)
    constexpr int FJ = BN / 32;        // frags per wave (cols)
    constexpr int WM = BM / 2;
    constexpr int WN = BN / 2;

    const int z = blockIdx.z;
    const ushort_t* B   = (z == 0) ? B0  : (z == 1) ? B1  : B2;
    const float*    bia = (z == 0) ? bi0 : (z == 1) ? bi1 : bi2;
    void*           C   = (z == 0) ? C0  : (z == 1) ? C1  : C2;
    const int mode      = (z == 0) ? mode0 : (z == 1) ? mode1 : mode2;

    __shared__ __align__(16) ushort_t As[BM][32];
    __shared__ __align__(16) ushort_t Bs[BN][32];

    const int t    = threadIdx.x;
    const int w    = t >> 6;
    const int L    = t & 63;
    const int r16  = L & 15;
    const int quad = L >> 4;
    const int wm   = w & 1;
    const int wn   = w >> 1;

    const int m0 = blockIdx.y * BM;
    const int n0 = blockIdx.x * BN;

    const int srow = t >> 2;        // staging row (+ c*64)
    const int skc  = (t & 3) * 8;   // k element offset

    const ushort_t* ap = A + (size_t)(m0 + srow) * GK + skc;
    const ushort_t* bp = B + (size_t)(n0 + srow) * GK + skc;

    floatx4 acc[FI][FJ];
#pragma unroll
    for (int i = 0; i < FI; ++i)
#pragma unroll
        for (int j = 0; j < FJ; ++j) acc[i][j] = (floatx4){0.f, 0.f, 0.f, 0.f};

    short8 areg[AC], breg[BC];
#pragma unroll
    for (int c = 0; c < AC; ++c) areg[c] = *(const short8*)(ap + (size_t)c * 64 * GK);
#pragma unroll
    for (int c = 0; c < BC; ++c) breg[c] = *(const short8*)(bp + (size_t)c * 64 * GK);

    for (int ks = 0; ks < GK / 32; ++ks) {
        __syncthreads();
#pragma unroll
        for (int c = 0; c < AC; ++c) *(short8*)&As[c * 64 + srow][skc] = areg[c];
#pragma unroll
        for (int c = 0; c < BC; ++c) *(short8*)&Bs[c * 64 + srow][skc] = breg[c];
        __syncthreads();
        if (ks < GK / 32 - 1) {
            ap += 32; bp += 32;
#pragma unroll
            for (int c = 0; c < AC; ++c) areg[c] = *(const short8*)(ap + (size_t)c * 64 * GK);
#pragma unroll
            for (int c = 0; c < BC; ++c) breg[c] = *(const short8*)(bp + (size_t)c * 64 * GK);
        }
        short8 af[FI], bf[FJ];
#pragma unroll
        for (int fi = 0; fi < FI; ++fi)
            af[fi] = *(const short8*)&As[wm * WM + fi * 16 + r16][quad * 8];
#pragma unroll
        for (int fj = 0; fj < FJ; ++fj)
            bf[fj] = *(const short8*)&Bs[wn * WN + fj * 16 + r16][quad * 8];
#pragma unroll
        for (int fi = 0; fi < FI; ++fi)
#pragma unroll
            for (int fj = 0; fj < FJ; ++fj)
                acc[fi][fj] = __builtin_amdgcn_mfma_f32_16x16x32_bf16(
                    af[fi], bf[fj], acc[fi][fj], 0, 0, 0);
    }

#pragma unroll
    for (int fj = 0; fj < FJ; ++fj) {
        const int col = n0 + wn * WN + fj * 16 + r16;
        const float bv = bia[col];
#pragma unroll
        for (int fi = 0; fi < FI; ++fi) {
            const int row0 = m0 + wm * WM + fi * 16 + 4 * quad;
            floatx4 c = acc[fi][fj];
            if (mode == 2) {
                float* Cf = (float*)C;
#pragma unroll
                for (int i = 0; i < 4; ++i)
                    Cf[(size_t)(row0 + i) * GN + col] = c[i] + bv;
            } else if (mode == 0) {
                ushort_t* Cb = (ushort_t*)C;
#pragma unroll
                for (int i = 0; i < 4; ++i)
                    Cb[(size_t)(row0 + i) * GN + col] = f2bf(c[i] + bv);
            } else {  // transposed: vT[col][token]
                ushort_t* Cb = (ushort_t*)C;
                ushort4 pk;
                pk.x = f2bf(c[0] + bv); pk.y = f2bf(c[1] + bv);
                pk.z = f2bf(c[2] + bv); pk.w = f2bf(c[3] + bv);
                *(ushort4*)(Cb + (size_t)col * GM + row0) = pk;
            }
        }
    }
}

// ---------------------------------------------------------------------------
// MFMA flash attention, fixed-max softmax (m=0), split-j over NCH chunks.
// R3: per-wave i-tile doubled to 32 q-rows (2 A-fragments). Rationale: R0-R2
// are all pinned at ~6.9 TB/s aggregate vector-load traffic (1.31 GB/dispatch)
// with every pipe idle; K/V re-reads are 1.0 GB of that. Serving 32 q-rows
// per K/V tile load halves the K/V amplification -> ~830 MB/dispatch.
// Block = 4 waves = heads hg*4..+3 of one 32-row i-block; j-chunk 512.
// K/V frags direct global->VGPR double-buffered; bias LDS double-buffered;
// per-wave P transpose in LDS (no barrier); fp32 split-j partials.
// ---------------------------------------------------------------------------
#define NT   (NTOK / 32)
#define NCH  4
#define NTCH (NT / NCH)          // 16 j-tiles per chunk
#define JCH  (NTOK / NCH)        // 512 columns per chunk
#define IB   32                  // q-rows per block

__global__ __launch_bounds__(256) void attn4(
    const ushort_t* __restrict__ q, const ushort_t* __restrict__ k,
    const ushort_t* __restrict__ vT, const float* __restrict__ bias,
    float* __restrict__ opart, float* __restrict__ lpart)
{
    __shared__ float    Bb[2][4][IB][33];   // [buf][head][i][j pad33] 33.8 KB
    __shared__ ushort_t Ps[4][16][40];      // [wave][row][col pad40]   5.1 KB

    const int b    = blockIdx.x;            // 256 = 64 i-blocks x 4 hg
    const int ch   = blockIdx.y;
    const int jb   = ch * JCH;
    const int hg   = (b >> 3) & 3;
    const int it   = (b & 7) | ((b >> 5) << 3);   // [0,64)
    const int i0   = it * IB;
    const int t    = threadIdx.x;
    const int w    = t >> 6;
    const int L    = t & 63;
    const int r16  = L & 15;
    const int quad = L >> 4;
    const int h    = hg * 4 + w;

#define kAddr(J0, JH, KC) (k  + (size_t)((J0) + (JH)*16 + r16) * DM + h*DH + (KC)*32 + quad*8)
#define vAddr(J0, DB)     (vT + (size_t)(h*DH + (DB)*16 + r16) * NTOK + (J0) + quad*8)
#define bAddr(J0, CI)     (bias + ((size_t)(i0 + (CI)*8 + (t>>5)) * NTOK + (J0) + (t&31)) * NH + hg*4)

    // resident Q A-frags: 2 row-fragments x 2 k-chunks
    short8 qf[2][2];
#pragma unroll
    for (int r = 0; r < 2; ++r)
#pragma unroll
        for (int kc = 0; kc < 2; ++kc)
            qf[r][kc] = *(const short8*)(q + (size_t)(i0 + r * 16 + r16) * DM
                                           + h * DH + kc * 32 + quad * 8);

    short8 kf[2][4];   // [buf][jh*2+kc]
    short8 vf[2][4];   // [buf][db]
    float4 bst[4];

    // prologue: first tile of this chunk (bias first: longest latency)
    bst[0] = *(const float4*)bAddr(jb, 0);
    bst[1] = *(const float4*)bAddr(jb, 1);
    bst[2] = *(const float4*)bAddr(jb, 2);
    bst[3] = *(const float4*)bAddr(jb, 3);
    kf[0][0] = *(const short8*)kAddr(jb, 0, 0);
    kf[0][1] = *(const short8*)kAddr(jb, 0, 1);
    kf[0][2] = *(const short8*)kAddr(jb, 1, 0);
    kf[0][3] = *(const short8*)kAddr(jb, 1, 1);
    vf[0][0] = *(const short8*)vAddr(jb, 0);
    vf[0][1] = *(const short8*)vAddr(jb, 1);
    vf[0][2] = *(const short8*)vAddr(jb, 2);
    vf[0][3] = *(const short8*)vAddr(jb, 3);
#pragma unroll
    for (int ci = 0; ci < 4; ++ci) {
        Bb[0][0][ci * 8 + (t >> 5)][t & 31] = bst[ci].x;
        Bb[0][1][ci * 8 + (t >> 5)][t & 31] = bst[ci].y;
        Bb[0][2][ci * 8 + (t >> 5)][t & 31] = bst[ci].z;
        Bb[0][3][ci * 8 + (t >> 5)][t & 31] = bst[ci].w;
    }
    __syncthreads();

    floatx4 o[2][4];
#pragma unroll
    for (int r = 0; r < 2; ++r)
#pragma unroll
        for (int d = 0; d < 4; ++d) o[r][d] = (floatx4){0.f, 0.f, 0.f, 0.f};
    float lrow[2][4] = {{0.f,0.f,0.f,0.f},{0.f,0.f,0.f,0.f}};

#define TILE(JT, CUR, NXT)                                                      \
  {                                                                             \
    const bool pre = (JT) < NTCH - 1;                                           \
    const int j0n = jb + ((JT) + 1) * 32;                                       \
    if (pre) {                                                                  \
      bst[0] = *(const float4*)bAddr(j0n, 0);                                   \
      bst[1] = *(const float4*)bAddr(j0n, 1);                                   \
      bst[2] = *(const float4*)bAddr(j0n, 2);                                   \
      bst[3] = *(const float4*)bAddr(j0n, 3);                                   \
      kf[NXT][0] = *(const short8*)kAddr(j0n, 0, 0);                            \
      kf[NXT][1] = *(const short8*)kAddr(j0n, 0, 1);                            \
      kf[NXT][2] = *(const short8*)kAddr(j0n, 1, 0);                            \
      kf[NXT][3] = *(const short8*)kAddr(j0n, 1, 1);                            \
      vf[NXT][0] = *(const short8*)vAddr(j0n, 0);                               \
      vf[NXT][1] = *(const short8*)vAddr(j0n, 1);                               \
      vf[NXT][2] = *(const short8*)vAddr(j0n, 2);                               \
      vf[NXT][3] = *(const short8*)vAddr(j0n, 3);                               \
    }                                                                           \
    floatx4 s00 = (floatx4){0.f,0.f,0.f,0.f};                                   \
    floatx4 s01 = (floatx4){0.f,0.f,0.f,0.f};                                   \
    floatx4 s10 = (floatx4){0.f,0.f,0.f,0.f};                                   \
    floatx4 s11 = (floatx4){0.f,0.f,0.f,0.f};                                   \
    s00 = __builtin_amdgcn_mfma_f32_16x16x32_bf16(qf[0][0], kf[CUR][0], s00, 0,0,0); \
    s00 = __builtin_amdgcn_mfma_f32_16x16x32_bf16(qf[0][1], kf[CUR][1], s00, 0,0,0); \
    s01 = __builtin_amdgcn_mfma_f32_16x16x32_bf16(qf[0][0], kf[CUR][2], s01, 0,0,0); \
    s01 = __builtin_amdgcn_mfma_f32_16x16x32_bf16(qf[0][1], kf[CUR][3], s01, 0,0,0); \
    s10 = __builtin_amdgcn_mfma_f32_16x16x32_bf16(qf[1][0], kf[CUR][0], s10, 0,0,0); \
    s10 = __builtin_amdgcn_mfma_f32_16x16x32_bf16(qf[1][1], kf[CUR][1], s10, 0,0,0); \
    s11 = __builtin_amdgcn_mfma_f32_16x16x32_bf16(qf[1][0], kf[CUR][2], s11, 0,0,0); \
    s11 = __builtin_amdgcn_mfma_f32_16x16x32_bf16(qf[1][1], kf[CUR][3], s11, 0,0,0); \
    _Pragma("unroll")                                                           \
    for (int ii = 0; ii < 4; ++ii) {                                            \
      const float bv0 = Bb[CUR][w][4 * quad + ii][r16];                         \
      const float bv1 = Bb[CUR][w][4 * quad + ii][16 + r16];                    \
      const float p0 = __expf(fmaf(s00[ii], SCALE, bv0));                       \
      const float p1 = __expf(fmaf(s01[ii], SCALE, bv1));                       \
      lrow[0][ii] += p0 + p1;                                                   \
      Ps[w][4 * quad + ii][r16]      = f2bf(p0);                                \
      Ps[w][4 * quad + ii][16 + r16] = f2bf(p1);                                \
    }                                                                           \
    {                                                                           \
      short8 pf = *(const short8*)&Ps[w][r16][quad * 8];                        \
      o[0][0] = __builtin_amdgcn_mfma_f32_16x16x32_bf16(pf, vf[CUR][0], o[0][0], 0,0,0); \
      o[0][1] = __builtin_amdgcn_mfma_f32_16x16x32_bf16(pf, vf[CUR][1], o[0][1], 0,0,0); \
      o[0][2] = __builtin_amdgcn_mfma_f32_16x16x32_bf16(pf, vf[CUR][2], o[0][2], 0,0,0); \
      o[0][3] = __builtin_amdgcn_mfma_f32_16x16x32_bf16(pf, vf[CUR][3], o[0][3], 0,0,0); \
    }                                                                           \
    _Pragma("unroll")                                                           \
    for (int ii = 0; ii < 4; ++ii) {                                            \
      const float bv0 = Bb[CUR][w][16 + 4 * quad + ii][r16];                    \
      const float bv1 = Bb[CUR][w][16 + 4 * quad + ii][16 + r16];               \
      const float p0 = __expf(fmaf(s10[ii], SCALE, bv0));                       \
      const float p1 = __expf(fmaf(s11[ii], SCALE, bv1));                       \
      lrow[1][ii] += p0 + p1;                                                   \
      Ps[w][4 * quad + ii][r16]      = f2bf(p0);                                \
      Ps[w][4 * quad + ii][16 + r16] = f2bf(p1);                                \
    }                                                                           \
    {                                                                           \
      short8 pf = *(const short8*)&Ps[w][r16][quad * 8];                        \
      o[1][0] = __builtin_amdgcn_mfma_f32_16x16x32_bf16(pf, vf[CUR][0], o[1][0], 0,0,0); \
      o[1][1] = __builtin_amdgcn_mfma_f32_16x16x32_bf16(pf, vf[CUR][1], o[1][1], 0,0,0); \
      o[1][2] = __builtin_amdgcn_mfma_f32_16x16x32_bf16(pf, vf[CUR][2], o[1][2], 0,0,0); \
      o[1][3] = __builtin_amdgcn_mfma_f32_16x16x32_bf16(pf, vf[CUR][3], o[1][3], 0,0,0); \
    }                                                                           \
    if (pre) {                                                                  \
      _Pragma("unroll")                                                         \
      for (int ci = 0; ci < 4; ++ci) {                                          \
        Bb[NXT][0][ci * 8 + (t >> 5)][t & 31] = bst[ci].x;                      \
        Bb[NXT][1][ci * 8 + (t >> 5)][t & 31] = bst[ci].y;                      \
        Bb[NXT][2][ci * 8 + (t >> 5)][t & 31] = bst[ci].z;                      \
        Bb[NXT][3][ci * 8 + (t >> 5)][t & 31] = bst[ci].w;                      \
      }                                                                         \
    }                                                                           \
    __syncthreads();                                                            \
  }

    for (int jt = 0; jt < NTCH; jt += 2) {
        TILE(jt, 0, 1)
        TILE(jt + 1, 1, 0)
    }

    // partial row-sums: reduce l across the 16 column-lanes of each row
#pragma unroll
    for (int r = 0; r < 2; ++r) {
        float lred[4];
#pragma unroll
        for (int ii = 0; ii < 4; ++ii) {
            float s = lrow[r][ii];
#pragma unroll
            for (int d = 1; d < 16; d <<= 1) s += __shfl_xor(s, d);
            lred[ii] = s;
        }
        if (r16 == 0) {
#pragma unroll
            for (int ii = 0; ii < 4; ++ii)
                lpart[(size_t)ch * NH * NTOK + (size_t)h * NTOK
                      + i0 + r * 16 + 4 * quad + ii] = lred[ii];
        }
    }

    float* op = opart + (size_t)ch * NTOK * DM;
#pragma unroll
    for (int r = 0; r < 2; ++r)
#pragma unroll
        for (int db = 0; db < 4; ++db)
#pragma unroll
            for (int ii = 0; ii < 4; ++ii)
                op[(size_t)(i0 + r * 16 + 4 * quad + ii) * DM
                   + h * DH + db * 16 + r16] = o[r][db][ii];
#undef TILE
#undef kAddr
#undef vAddr
#undef bAddr
}

// ---------------------------------------------------------------------------
// merge split-j partials: o = (sum_c opart[c]) / (sum_c lpart[c]); bf16 out.
// ---------------------------------------------------------------------------
__global__ __launch_bounds__(256) void attn_fin(
    const float* __restrict__ opart, const float* __restrict__ lpart,
    ushort_t* __restrict__ ao)
{
    const int idx = blockIdx.x * 256 + threadIdx.x;   // float4 index
    const int n   = idx >> 8;                         // 256 float4 per row
    const int d4  = idx & 255;
    const int h   = d4 >> 4;
    const size_t base = (size_t)n * DM + (size_t)d4 * 4;
    float4 s = {0.f, 0.f, 0.f, 0.f};
    float  l = 0.f;
#pragma unroll
    for (int c = 0; c < NCH; ++c) {
        float4 p = *(const float4*)(opart + (size_t)c * NTOK * DM + base);
        s.x += p.x; s.y += p.y; s.z += p.z; s.w += p.w;
        l += lpart[(size_t)c * NH * NTOK + (size_t)h * NTOK + n];
    }
    const float inv = 1.f / l;
    ushort4 o;
    o.x = f2bf(s.x * inv); o.y = f2bf(s.y * inv);
    o.z = f2bf(s.z * inv); o.w = f2bf(s.w * inv);
    ((ushort4*)ao)[idx] = o;
}

// ---------------------------------------------------------------------------
// launch
// ---------------------------------------------------------------------------
extern "C" void kernel_launch(void* const* d_in, const int* in_sizes, int n_in,
                              void* d_out, int out_size, void* d_ws, size_t ws_size,
                              hipStream_t stream)
{
    const float* x  = (const float*)d_in[0];
    const float* eb = (const float*)d_in[1];
    const float* Wq = (const float*)d_in[2];
    const float* bq = (const float*)d_in[3];
    const float* Wk = (const float*)d_in[4];
    const float* bk = (const float*)d_in[5];
    const float* Wv = (const float*)d_in[6];
    const float* bv = (const float*)d_in[7];
    const float* Wo = (const float*)d_in[8];
    const float* bo = (const float*)d_in[9];
    float* out = (float*)d_out;
    (void)in_sizes; (void)n_in; (void)out_size; (void)ws_size;

    const size_t E1 = (size_t)1024 * 1024;
    ushort_t* wsb = (ushort_t*)d_ws;
    ushort_t* xb  = wsb;            // 2M
    ushort_t* Wqb = wsb + 2 * E1;   // 1M each
    ushort_t* Wkb = wsb + 3 * E1;
    ushort_t* Wvb = wsb + 4 * E1;
    ushort_t* Wob = wsb + 5 * E1;
    ushort_t* qb  = wsb + 6 * E1;   // 2M each
    ushort_t* kb  = wsb + 8 * E1;
    ushort_t* vTb = wsb + 10 * E1;
    ushort_t* aob = wsb + 12 * E1;
    // split-j partials after aob: NCH x [N][DM] fp32 + NCH x [NH][N] fp32
    float* opart = (float*)(wsb + 14 * E1);
    float* lpart = opart + (size_t)NCH * NTOK * DM;

    convert5<<<6144, 256, 0, stream>>>(x, Wq, Wk, Wv, Wo, wsb);

    // QKV projections: 128x64 tiles -> grid 16x16x3 = 768 blocks (3/CU)
    {
        dim3 grid(GN / 64, GM / 128, 3);
        gemm_bt<128, 64><<<grid, 256, 0, stream>>>(
            xb, Wqb, Wkb, Wvb, bq, bk, bv,
            qb, kb, vTb, 0, 0, 1);
    }
    // fused attention: 32-row i-blocks x 4 heads, split-j -> merge
    {
        dim3 grid((NTOK / IB) * 4, NCH, 1);
        attn4<<<grid, 256, 0, stream>>>(qb, kb, vTb, eb, opart, lpart);
    }
    attn_fin<<<NTOK * DM / 4 / 256, 256, 0, stream>>>(opart, lpart, aob);

    // output projection: 64x64 tiles -> grid 16x32 = 512 blocks (2/CU)
    {
        dim3 grid(GN / 64, GM / 64, 1);
        gemm_bt<64, 64><<<grid, 256, 0, stream>>>(
            aob, Wob, Wob, Wob, bo, bo, bo,
            out, out, out, 2, 2, 2);
    }
}